// Round 9
// baseline (161.134 us; speedup 1.0000x reference)
//
#include <hip/hip_runtime.h>

#define T_PTS 8192
#define D_DIM 128
#define C_OUT 16
#define NSPLIT 8
#define JSPAN (T_PTS / NSPLIT) /* 1024 */
#define NJT (JSPAN / 64)       /* 16 */
#define LB 136                 /* LDS row stride in fp16 (272 B) — R6-proven staging layout */
#define LSTR 132               /* fp32 LDS stride for y part */
#define NC (NSPLIT * 4)        /* 32 candidates per row */
#define MSTR 65                /* merge scratch row stride */
#define RS_BLOCKS (T_PTS / 2)  /* staged-rescore blocks (2 rows each) */
#define CSTR 133               /* rescore staging stride in floats */

typedef _Float16 half8 __attribute__((ext_vector_type(8)));
typedef __attribute__((ext_vector_type(4))) float f32x4;
typedef unsigned short ushort_t;
typedef unsigned int uint_t;

// ---------------------------------------------------------------- prep: fp32->fp16 + rowwise sumsq
__global__ void prep_kernel(const float* __restrict__ X, _Float16* __restrict__ Xh,
                            float* __restrict__ sq) {
    const int tid = threadIdx.x;
    const int row = blockIdx.x * 16 + (tid >> 4);
    const int c8 = (tid & 15) * 8;
    const float4* p = (const float4*)(X + row * D_DIM + c8);
    const float4 a = p[0], b = p[1];
    half8 o;
    o[0] = (_Float16)a.x; o[1] = (_Float16)a.y; o[2] = (_Float16)a.z; o[3] = (_Float16)a.w;
    o[4] = (_Float16)b.x; o[5] = (_Float16)b.y; o[6] = (_Float16)b.z; o[7] = (_Float16)b.w;
    *(half8*)(Xh + row * D_DIM + c8) = o;
    float s = a.x * a.x + a.y * a.y + a.z * a.z + a.w * a.w
            + b.x * b.x + b.y * b.y + b.z * b.z + b.w * b.w;
    s += __shfl_xor(s, 1); s += __shfl_xor(s, 2);
    s += __shfl_xor(s, 4); s += __shfl_xor(s, 8);
    if ((tid & 15) == 0) sq[row] = s;
}

// ---------------------------------------------------------------- MFMA fp16 scores
// LDS-staged j-tiles (R6-proven: coalesced global stores, ds_read_b128 frags — kills
// the 16-line TA gather that bounded R8) + R8's cheap packed-key min/med3 selection.
// fp16 keys are CANDIDATE-RECALL ONLY; fp32 rescore in mid_kernel decides final order.
// REGISTER BUDGET: bfrag 64 VGPR persistent — __launch_bounds__(256,2) mandatory;
// (256,4) spilled to scratch and was 2.4x slower (round 7).
__launch_bounds__(256, 2)
__global__ void nn_kernel(const _Float16* __restrict__ Xh, const float* __restrict__ sq,
                          ushort_t* __restrict__ cand) {
    __shared__ _Float16 Ash[64 * LB];   // 17408 B j-tile; aliased by mj after the loop
    __shared__ float mk[64 * MSTR];     // 16640 B
    int* mj = (int*)Ash;                // 16640 B <= 17408 B

    const int tid = threadIdx.x;
    const int w = tid >> 6;
    const int lane = tid & 63;
    const int quad = lane >> 4;
    const int l15 = lane & 15;
    const int i0 = blockIdx.x * 64;
    const int sp = blockIdx.y;
    const int j0 = sp * JSPAN;

    // B-operand frags (i side), loaded once per block from global
    half8 bfrag[4][4];
#pragma unroll
    for (int n = 0; n < 4; ++n)
#pragma unroll
        for (int k = 0; k < 4; ++k)
            bfrag[n][k] = *(const half8*)(Xh + (i0 + n * 16 + l15) * D_DIM + k * 32 + quad * 8);

    float c0[4], c1[4], c2[4], c3[4], sk[4];
#pragma unroll
    for (int n = 0; n < 4; ++n) { c0[n] = c1[n] = c2[n] = c3[n] = sk[n] = 1e30f; }

    int icol[4];
#pragma unroll
    for (int n = 0; n < 4; ++n) icol[n] = i0 + n * 16 + l15;

    const bool blk_excl = (sp == (i0 / JSPAN));
    const int excl_jt = (i0 & (JSPAN - 1)) >> 6;

    for (int jt = 0; jt < NJT; ++jt) {
        const int jbase = j0 + jt * 64;
        __syncthreads();
        // stage 64 j-rows: 64 x 256 B, coalesced 16B chunks (R6-verbatim)
#pragma unroll
        for (int it = 0; it < 4; ++it) {
            int f = tid + it * 256;  // 0..1023
            int row = f >> 4, ch = f & 15;
            *(uint4*)(Ash + row * LB + ch * 8) = *(const uint4*)(Xh + (jbase + row) * D_DIM + ch * 8);
        }
        __syncthreads();

        half8 af[4];
#pragma unroll
        for (int k = 0; k < 4; ++k)
            af[k] = *(const half8*)(Ash + (w * 16 + l15) * LB + k * 32 + quad * 8);
        const f32x4 sq4 = *(const f32x4*)(sq + jbase + w * 16 + quad * 4);
        const int jg = jbase + w * 16 + quad * 4;  // + r
        const bool excl = blk_excl && (jt == excl_jt);
        const uint_t ib = (uint_t)(jt * 4);

#pragma unroll
        for (int n = 0; n < 4; ++n) {
            f32x4 acc = {0.f, 0.f, 0.f, 0.f};
#pragma unroll
            for (int k = 0; k < 4; ++k)
                acc = __builtin_amdgcn_mfma_f32_16x16x32_f16(af[k], bfrag[n][k], acc, 0, 0, 0);
            float q0 = fmaf(-2.f, acc[0], sq4[0]);
            float q1 = fmaf(-2.f, acc[1], sq4[1]);
            float q2 = fmaf(-2.f, acc[2], sq4[2]);
            float q3 = fmaf(-2.f, acc[3], sq4[3]);
            if (excl) {  // wave-uniform branch; self-exclusion BEFORE packing/selection
                if (jg + 0 == icol[n]) q0 = 1e30f;
                if (jg + 1 == icol[n]) q1 = 1e30f;
                if (jg + 2 == icol[n]) q2 = 1e30f;
                if (jg + 3 == icol[n]) q3 = 1e30f;
            }
            const float p0 = __uint_as_float((__float_as_uint(q0) & 0xFFFFFFC0u) | (ib + 0));
            const float p1 = __uint_as_float((__float_as_uint(q1) & 0xFFFFFFC0u) | (ib + 1));
            const float p2 = __uint_as_float((__float_as_uint(q2) & 0xFFFFFFC0u) | (ib + 2));
            const float p3 = __uint_as_float((__float_as_uint(q3) & 0xFFFFFFC0u) | (ib + 3));
            const float min01 = fminf(p0, p1), max01 = fmaxf(p0, p1);
            const float min23 = fminf(p2, p3), max23 = fmaxf(p2, p3);
            const float kmin = fminf(min01, min23);
            const float ksec = fminf(fmaxf(min01, min23), fminf(max01, max23));
            c3[n] = __builtin_amdgcn_fmed3f(c2[n], c3[n], kmin);
            c2[n] = __builtin_amdgcn_fmed3f(c1[n], c2[n], kmin);
            c1[n] = __builtin_amdgcn_fmed3f(c0[n], c1[n], kmin);
            c0[n] = fminf(c0[n], kmin);
            sk[n] = fminf(sk[n], ksec);
        }
    }

    // fold side value into each chain
#pragma unroll
    for (int n = 0; n < 4; ++n) {
        const float v = sk[n];
        c3[n] = __builtin_amdgcn_fmed3f(c2[n], c3[n], v);
        c2[n] = __builtin_amdgcn_fmed3f(c1[n], c2[n], v);
        c1[n] = __builtin_amdgcn_fmed3f(c0[n], c1[n], v);
        c0[n] = fminf(c0[n], v);
    }

    __syncthreads();  // Ash (j-tile) dead; mj aliases it from here
    const int s = w * 4 + quad;
    const int jdec0 = j0 + w * 16 + quad * 4;  // + (p>>2)*64 + (p&3)
#pragma unroll
    for (int n = 0; n < 4; ++n) {
        const int il = n * 16 + l15;
        const int base = il * MSTR + s * 4;
        float cc[4] = {c0[n], c1[n], c2[n], c3[n]};
#pragma unroll
        for (int e = 0; e < 4; ++e) {
            const uint_t p = __float_as_uint(cc[e]) & 63u;
            mk[base + e] = cc[e];
            mj[base + e] = jdec0 + (int)(p >> 2) * 64 + (int)(p & 3);
        }
    }
    __syncthreads();
    if (tid < 64) {
        float a0 = 1e30f, a1 = 1e30f, a2 = 1e30f, a3 = 1e30f;
        int b0 = 0, b1 = 0, b2 = 0, b3 = 0;
        for (int e = 0; e < 64; ++e) {
            float k = mk[tid * MSTR + e];
            int j = mj[tid * MSTR + e];
            bool l0 = k < a0, l1 = k < a1, l2 = k < a2, l3 = k < a3;
            a3 = l2 ? a2 : (l3 ? k : a3); b3 = l2 ? b2 : (l3 ? j : b3);
            a2 = l1 ? a1 : (l2 ? k : a2); b2 = l1 ? b1 : (l2 ? j : b2);
            a1 = l0 ? a0 : (l1 ? k : a1); b1 = l0 ? b0 : (l1 ? j : b1);
            a0 = l0 ? k : a0;             b0 = l0 ? j : b0;
        }
        const int gi = i0 + tid;
        ushort_t* c = cand + (sp * T_PTS + gi) * 4;
        c[0] = (ushort_t)b0; c[1] = (ushort_t)b1; c[2] = (ushort_t)b2; c[3] = (ushort_t)b3;
    }
}

// ---------------------------------------------------------------- mid: LDS-staged rescore + Y=XW+b
// CRITICAL: the rescore dot stays a per-thread sequential fma chain
// (`ssum += a.x*b2.x;` x4, loop over q) — the accumulation order that matched the
// reference in rounds 1/4/6/8. LDS staging copies bits exactly; values unchanged.
__global__ void mid_kernel(const float* __restrict__ X, const float* __restrict__ sq,
                           const ushort_t* __restrict__ cand, int* __restrict__ nbrs,
                           const float* __restrict__ W, const float* __restrict__ b,
                           float* __restrict__ Y, float* __restrict__ out) {
    __shared__ float Cs[64 * CSTR];   // 34048 B; y-part aliases Xs/Ws onto it
    __shared__ int jrowLds[64];
    __shared__ float keys[2][NC];
    __shared__ int idxs[2][NC];
    const int tid = threadIdx.x;

    if (blockIdx.x < RS_BLOCKS) {
        const int ibase = blockIdx.x * 2;
        if (tid < 64) {
            const int ii = tid >> 5, t = tid & 31;
            jrowLds[tid] = (int)cand[((t >> 2) * T_PTS + (ibase + ii)) * 4 + (t & 3)];
        }
        __syncthreads();
        // stage 64 candidate rows, coalesced: 32 lanes x consecutive float4 per row
#pragma unroll
        for (int it = 0; it < 8; ++it) {
            const int f = tid + it * 256;     // 0..2047
            const int cr = f >> 5, q = f & 31;
            const int j = jrowLds[cr];
            *(float4*)(Cs + cr * CSTR + q * 4) = *(const float4*)(X + j * D_DIM + q * 4);
        }
        __syncthreads();
        if (tid < 64) {
            const int ii = tid >> 5, t = tid & 31;
            const int i = ibase + ii;
            const int j = jrowLds[tid];
            const float4* xi = (const float4*)(X + i * D_DIM);
            const float* xb = Cs + tid * CSTR;
            float ssum = 0.f;
#pragma unroll
            for (int q = 0; q < 32; ++q) {
                const float4 a = xi[q];
                const float4 b2 = *(const float4*)(xb + q * 4);
                ssum += a.x * b2.x; ssum += a.y * b2.y; ssum += a.z * b2.z; ssum += a.w * b2.w;
            }
            float key = sq[j] - 2.f * ssum;
            if (j == i) key = 1e30f;
            keys[ii][t] = key;
            idxs[ii][t] = j;
        }
        __syncthreads();
        if (tid < 64 && (tid & 31) == 0) {
            const int ii = tid >> 5;
            float m0 = 1e30f, m1 = 1e30f;
            int n0 = 0x7fffffff, n1 = 0x7fffffff;
            for (int e = 0; e < NC; ++e) {
                float k = keys[ii][e];
                int j = idxs[ii][e];
                bool lt0 = (k < m0) || (k == m0 && j < n0);
                bool lt1 = (k < m1) || (k == m1 && j < n1);
                if (lt0) { m1 = m0; n1 = n0; m0 = k; n0 = j; }
                else if (lt1) { m1 = k; n1 = j; }
            }
            const int i = ibase + ii;
            nbrs[i * 2 + 0] = n0;
            nbrs[i * 2 + 1] = n1;
        }
    } else {
        // Y = X@W + b, plus logits rows [0,T)
        float* Xs = Cs;                 // 16*LSTR = 2112 floats
        float* Ws = Cs + 4096;          // 2048 floats; 6144 <= 8512 total
        const int r0 = (blockIdx.x - RS_BLOCKS) * 16;
        const float4* src = (const float4*)(X + r0 * D_DIM);
#pragma unroll
        for (int it = 0; it < 2; ++it) {
            int f = tid + it * 256;  // 0..511
            int row = f >> 5, kq = f & 31;
            *(float4*)(Xs + row * LSTR + kq * 4) = src[row * 32 + kq];
        }
#pragma unroll
        for (int it = 0; it < 2; ++it) {
            int f = tid + it * 256;
            ((float4*)Ws)[f] = ((const float4*)W)[f];
        }
        __syncthreads();
        const int r = tid >> 4, c = tid & 15;
        float s = b[c];
#pragma unroll
        for (int d = 0; d < D_DIM; ++d) s += Xs[r * LSTR + d] * Ws[d * C_OUT + c];
        const int row = r0 + r;
        Y[row * C_OUT + c] = s;
        out[row * C_OUT + c] = s;
    }
}

// ---------------------------------------------------------------- synthetic rows: lerp of Y
__global__ void syn_kernel(const float* __restrict__ Y, const int* __restrict__ nbrs,
                           const int* __restrict__ nn_idx, const float* __restrict__ gaps,
                           float* __restrict__ out) {
    const int idx = blockIdx.x * 256 + threadIdx.x;
    const int m = idx >> 4;
    const int c = idx & 15;
    const int src = m >> 2;       // repeat(arange(T), 4)
    const int sel = nn_idx[m];    // 0 or 1
    const int ch = nbrs[src * 2 + sel];
    const float g = gaps[m];
    const float ys = Y[src * C_OUT + c];
    const float yc = Y[ch * C_OUT + c];
    out[(T_PTS + m) * C_OUT + c] = ys + g * (yc - ys);
}

extern "C" void kernel_launch(void* const* d_in, const int* in_sizes, int n_in,
                              void* d_out, int out_size, void* d_ws, size_t ws_size,
                              hipStream_t stream) {
    const float* X = (const float*)d_in[0];
    const int* nn_idx = (const int*)d_in[1];
    const float* gaps = (const float*)d_in[2];
    const float* W = (const float*)d_in[3];
    const float* b = (const float*)d_in[4];
    float* out = (float*)d_out;

    char* ws = (char*)d_ws;
    _Float16* Xh = (_Float16*)ws;                                  // 2 MB
    float* sq = (float*)(ws + 2097152);                            // 32 KB
    ushort_t* cand = (ushort_t*)(ws + 2097152 + 32768);            // 512 KB
    int* nbrs = (int*)(ws + 2097152 + 32768 + 524288);             // 64 KB
    float* Y = (float*)(ws + 2097152 + 32768 + 524288 + 65536);    // 512 KB

    prep_kernel<<<T_PTS / 16, 256, 0, stream>>>(X, Xh, sq);
    nn_kernel<<<dim3(T_PTS / 64, NSPLIT), 256, 0, stream>>>(Xh, sq, cand);
    mid_kernel<<<RS_BLOCKS + T_PTS / 16, 256, 0, stream>>>(X, sq, cand, nbrs, W, b, Y, out);
    syn_kernel<<<(4 * T_PTS * C_OUT) / 256, 256, 0, stream>>>(Y, nbrs, nn_idx, gaps, out);
}

// Round 10
// 118.414 us; speedup vs baseline: 1.3608x; 1.3608x over previous
//
#include <hip/hip_runtime.h>

#define T_PTS 8192
#define D_DIM 128
#define C_OUT 16
#define NSPLIT 8
#define JSPAN (T_PTS / NSPLIT) /* 1024 */
#define NJT (JSPAN / 64)       /* 16 */
#define LSTR 132               /* fp32 LDS stride for y kernel */
#define MSTR 65                /* merge scratch row stride */

typedef _Float16 half8 __attribute__((ext_vector_type(8)));
typedef __attribute__((ext_vector_type(4))) float f32x4;
typedef unsigned short ushort_t;
typedef unsigned int uint_t;

// Swizzled fp16 layout: Xs[tile=row>>4][k=0..3][lane=quad*16+(row&15)][8 halfs]
// lane's 16B = row (lane&15), dims k*32+(lane>>4)*8 .. +8  == MFMA A/B frag layout.
// => af/bfrag loads are base + lane*16B: perfectly coalesced, no LDS staging needed.

// ---------------------------------------------------------------- prep: fp32->fp16 swizzled + rowwise sumsq
__global__ void prep_kernel(const float* __restrict__ X, _Float16* __restrict__ Xs,
                            float* __restrict__ sq) {
    const int tid = threadIdx.x;
    const int row = blockIdx.x * 16 + (tid >> 4);
    const int ch = tid & 15;
    const float4* p = (const float4*)(X + row * D_DIM + ch * 8);
    const float4 a = p[0], b = p[1];
    half8 o;
    o[0] = (_Float16)a.x; o[1] = (_Float16)a.y; o[2] = (_Float16)a.z; o[3] = (_Float16)a.w;
    o[4] = (_Float16)b.x; o[5] = (_Float16)b.y; o[6] = (_Float16)b.z; o[7] = (_Float16)b.w;
    const int t = row >> 4, m = row & 15, k = ch >> 2, q = ch & 3;
    *(half8*)(Xs + t * 2048 + k * 512 + (q * 16 + m) * 8) = o;
    float s = a.x * a.x + a.y * a.y + a.z * a.z + a.w * a.w
            + b.x * b.x + b.y * b.y + b.z * b.z + b.w * b.w;
    s += __shfl_xor(s, 1); s += __shfl_xor(s, 2);
    s += __shfl_xor(s, 4); s += __shfl_xor(s, 8);
    if (ch == 0) sq[row] = s;
}

// ---------------------------------------------------------------- MFMA fp16 scores, barrier-free, coalesced frags
// fp16 keys are CANDIDATE-RECALL ONLY; fp32 rescore decides the final order.
// REGISTER BUDGET: bfrag 64 VGPR persistent — (256,2) mandatory; (256,4) spilled (round 7).
__launch_bounds__(256, 2)
__global__ void nn_kernel(const _Float16* __restrict__ Xs, const float* __restrict__ sq,
                          float* __restrict__ ckey, ushort_t* __restrict__ cidx) {
    __shared__ float mk[64 * MSTR];
    __shared__ int mj[64 * MSTR];

    const int tid = threadIdx.x;
    const int w = tid >> 6;
    const int lane = tid & 63;
    const int quad = lane >> 4;
    const int l15 = lane & 15;
    const int i0 = blockIdx.x * 64;
    const int sp = blockIdx.y;
    const int j0 = sp * JSPAN;

    // B-operand frags (i side): coalesced swizzled loads, held for the whole sweep
    half8 bfrag[4][4];
#pragma unroll
    for (int n = 0; n < 4; ++n)
#pragma unroll
        for (int k = 0; k < 4; ++k)
            bfrag[n][k] = *(const half8*)(Xs + ((i0 >> 4) + n) * 2048 + k * 512 + lane * 8);

    float c0[4], c1[4], c2[4], c3[4], sk[4];
#pragma unroll
    for (int n = 0; n < 4; ++n) { c0[n] = c1[n] = c2[n] = c3[n] = sk[n] = 1e30f; }

    int icol[4];
#pragma unroll
    for (int n = 0; n < 4; ++n) icol[n] = i0 + n * 16 + l15;

    const bool blk_excl = (sp == (i0 / JSPAN));
    const int excl_jt = (i0 & (JSPAN - 1)) >> 6;

    for (int jt = 0; jt < NJT; ++jt) {
        const int jbase = j0 + jt * 64;
        const int jtile = (jbase >> 4) + w;
        half8 af[4];
#pragma unroll
        for (int k = 0; k < 4; ++k)
            af[k] = *(const half8*)(Xs + jtile * 2048 + k * 512 + lane * 8);
        const f32x4 sq4 = *(const f32x4*)(sq + jbase + w * 16 + quad * 4);
        const int jg = jbase + w * 16 + quad * 4;  // + r
        const bool excl = blk_excl && (jt == excl_jt);
        const uint_t ib = (uint_t)(jt * 4);

#pragma unroll
        for (int n = 0; n < 4; ++n) {
            f32x4 acc = {0.f, 0.f, 0.f, 0.f};
#pragma unroll
            for (int k = 0; k < 4; ++k)
                acc = __builtin_amdgcn_mfma_f32_16x16x32_f16(af[k], bfrag[n][k], acc, 0, 0, 0);
            float q0 = fmaf(-2.f, acc[0], sq4[0]);
            float q1 = fmaf(-2.f, acc[1], sq4[1]);
            float q2 = fmaf(-2.f, acc[2], sq4[2]);
            float q3 = fmaf(-2.f, acc[3], sq4[3]);
            if (excl) {  // wave-uniform; self-exclusion BEFORE packing/selection
                if (jg + 0 == icol[n]) q0 = 1e30f;
                if (jg + 1 == icol[n]) q1 = 1e30f;
                if (jg + 2 == icol[n]) q2 = 1e30f;
                if (jg + 3 == icol[n]) q3 = 1e30f;
            }
            const float p0 = __uint_as_float((__float_as_uint(q0) & 0xFFFFFFC0u) | (ib + 0));
            const float p1 = __uint_as_float((__float_as_uint(q1) & 0xFFFFFFC0u) | (ib + 1));
            const float p2 = __uint_as_float((__float_as_uint(q2) & 0xFFFFFFC0u) | (ib + 2));
            const float p3 = __uint_as_float((__float_as_uint(q3) & 0xFFFFFFC0u) | (ib + 3));
            const float min01 = fminf(p0, p1), max01 = fmaxf(p0, p1);
            const float min23 = fminf(p2, p3), max23 = fmaxf(p2, p3);
            const float kmin = fminf(min01, min23);
            const float ksec = fminf(fmaxf(min01, min23), fminf(max01, max23));
            c3[n] = __builtin_amdgcn_fmed3f(c2[n], c3[n], kmin);
            c2[n] = __builtin_amdgcn_fmed3f(c1[n], c2[n], kmin);
            c1[n] = __builtin_amdgcn_fmed3f(c0[n], c1[n], kmin);
            c0[n] = fminf(c0[n], kmin);
            sk[n] = fminf(sk[n], ksec);
        }
    }

#pragma unroll
    for (int n = 0; n < 4; ++n) {
        const float v = sk[n];
        c3[n] = __builtin_amdgcn_fmed3f(c2[n], c3[n], v);
        c2[n] = __builtin_amdgcn_fmed3f(c1[n], c2[n], v);
        c1[n] = __builtin_amdgcn_fmed3f(c0[n], c1[n], v);
        c0[n] = fminf(c0[n], v);
    }

    const int s = w * 4 + quad;
    const int jdec0 = j0 + w * 16 + quad * 4;  // + (p>>2)*64 + (p&3)
#pragma unroll
    for (int n = 0; n < 4; ++n) {
        const int il = n * 16 + l15;
        const int base = il * MSTR + s * 4;
        float cc[4] = {c0[n], c1[n], c2[n], c3[n]};
#pragma unroll
        for (int e = 0; e < 4; ++e) {
            const uint_t p = __float_as_uint(cc[e]) & 63u;
            mk[base + e] = cc[e];
            mj[base + e] = jdec0 + (int)(p >> 2) * 64 + (int)(p & 3);
        }
    }
    __syncthreads();
    if (tid < 64) {
        float a0 = 1e30f, a1 = 1e30f, a2 = 1e30f, a3 = 1e30f;
        int b0 = 0, b1 = 0, b2 = 0, b3 = 0;
        for (int e = 0; e < 64; ++e) {
            float k = mk[tid * MSTR + e];
            int j = mj[tid * MSTR + e];
            bool l0 = k < a0, l1 = k < a1, l2 = k < a2, l3 = k < a3;
            a3 = l2 ? a2 : (l3 ? k : a3); b3 = l2 ? b2 : (l3 ? j : b3);
            a2 = l1 ? a1 : (l2 ? k : a2); b2 = l1 ? b1 : (l2 ? j : b2);
            a1 = l0 ? a0 : (l1 ? k : a1); b1 = l0 ? b0 : (l1 ? j : b1);
            a0 = l0 ? k : a0;             b0 = l0 ? j : b0;
        }
        const int gi = i0 + tid;
        f32x4 kv = {a0, a1, a2, a3};
        *(f32x4*)(ckey + (sp * T_PTS + gi) * 4) = kv;
        ushort_t* c = cidx + (sp * T_PTS + gi) * 4;
        c[0] = (ushort_t)b0; c[1] = (ushort_t)b1; c[2] = (ushort_t)b2; c[3] = (ushort_t)b3;
    }
}

// ---------------------------------------------------------------- global top-8 by fp16 key (of 32 candidates)
__global__ void merge8_kernel(const float* __restrict__ ckey, const ushort_t* __restrict__ cidx,
                              ushort_t* __restrict__ nb8) {
    __shared__ int idxs[256 * 33];
    const int tid = threadIdx.x;
    const int i = blockIdx.x * 256 + tid;
    float c0 = 1e30f, c1 = 1e30f, c2 = 1e30f, c3 = 1e30f;
    float c4 = 1e30f, c5 = 1e30f, c6 = 1e30f, c7 = 1e30f;
#pragma unroll
    for (int sp = 0; sp < NSPLIT; ++sp) {
        const f32x4 kk = *(const f32x4*)(ckey + (sp * T_PTS + i) * 4);   // coalesced
        const ushort_t* jj = cidx + (sp * T_PTS + i) * 4;                 // coalesced 8B
        ushort_t j4[4];
        *(uint2*)j4 = *(const uint2*)jj;
#pragma unroll
        for (int e4 = 0; e4 < 4; ++e4) {
            const uint_t e = (uint_t)(sp * 4 + e4);
            const float v = __uint_as_float((__float_as_uint(kk[e4]) & 0xFFFFFFC0u) | e);
            idxs[tid * 33 + e] = (int)j4[e4];
            // sorted-8 insert via med3
            c7 = __builtin_amdgcn_fmed3f(c6, c7, v);
            c6 = __builtin_amdgcn_fmed3f(c5, c6, v);
            c5 = __builtin_amdgcn_fmed3f(c4, c5, v);
            c4 = __builtin_amdgcn_fmed3f(c3, c4, v);
            c3 = __builtin_amdgcn_fmed3f(c2, c3, v);
            c2 = __builtin_amdgcn_fmed3f(c1, c2, v);
            c1 = __builtin_amdgcn_fmed3f(c0, c1, v);
            c0 = fminf(c0, v);
        }
    }
    float top[8] = {c0, c1, c2, c3, c4, c5, c6, c7};
    ushort_t o[8];
#pragma unroll
    for (int r = 0; r < 8; ++r) {
        const uint_t p = __float_as_uint(top[r]) & 63u;
        o[r] = (ushort_t)idxs[tid * 33 + (int)p];
    }
    *(uint2*)(nb8 + i * 8) = *(const uint2*)o;
    *(uint2*)(nb8 + i * 8 + 4) = *(const uint2*)(o + 4);
}

// ---------------------------------------------------------------- exact fp32 rescore of 8 candidates
// CRITICAL: per-thread sequential fma chain (`ssum += a.x*b2.x;` x4, loop over q) —
// the accumulation order that matched the reference in rounds 1/4/6/8/9.
__global__ void rescore8_kernel(const float* __restrict__ X, const float* __restrict__ sq,
                                const ushort_t* __restrict__ nb8, int* __restrict__ nbrs) {
    __shared__ float keys[32][9];
    __shared__ int idxs[32][9];
    const int tid = threadIdx.x;
    const int rr = tid >> 3;   // 0..31
    const int cc = tid & 7;
    const int i = blockIdx.x * 32 + rr;
    {
        const int j = (int)nb8[i * 8 + cc];
        const float4* xi = (const float4*)(X + i * D_DIM);
        const float4* xj = (const float4*)(X + j * D_DIM);
        float ssum = 0.f;
#pragma unroll
        for (int q = 0; q < 32; ++q) {
            const float4 a = xi[q], b2 = xj[q];
            ssum += a.x * b2.x; ssum += a.y * b2.y; ssum += a.z * b2.z; ssum += a.w * b2.w;
        }
        float key = sq[j] - 2.f * ssum;
        if (j == i) key = 1e30f;
        keys[rr][cc] = key;
        idxs[rr][cc] = j;
    }
    __syncthreads();
    if (tid < 32) {
        float m0 = 1e30f, m1 = 1e30f;
        int n0 = 0x7fffffff, n1 = 0x7fffffff;
        for (int e = 0; e < 8; ++e) {
            float k = keys[tid][e];
            int j = idxs[tid][e];
            bool lt0 = (k < m0) || (k == m0 && j < n0);
            bool lt1 = (k < m1) || (k == m1 && j < n1);
            if (lt0) { m1 = m0; n1 = n0; m0 = k; n0 = j; }
            else if (lt1) { m1 = k; n1 = j; }
        }
        const int i2 = blockIdx.x * 32 + tid;
        nbrs[i2 * 2 + 0] = n0;
        nbrs[i2 * 2 + 1] = n1;
    }
}

// ---------------------------------------------------------------- Y = X@W + b; also logits rows [0,T)
__launch_bounds__(256)
__global__ void y_kernel(const float* __restrict__ X, const float* __restrict__ W,
                         const float* __restrict__ b, float* __restrict__ Y,
                         float* __restrict__ out) {
    __shared__ float Xsl[16 * LSTR];
    __shared__ float Ws[D_DIM * C_OUT];
    const int tid = threadIdx.x;
    const int r0 = blockIdx.x * 16;
    const float4* src = (const float4*)(X + r0 * D_DIM);
#pragma unroll
    for (int it = 0; it < 2; ++it) {
        int f = tid + it * 256;  // 0..511
        int row = f >> 5, kq = f & 31;
        *(float4*)(Xsl + row * LSTR + kq * 4) = src[row * 32 + kq];
    }
#pragma unroll
    for (int it = 0; it < 2; ++it) {
        int f = tid + it * 256;
        ((float4*)Ws)[f] = ((const float4*)W)[f];
    }
    __syncthreads();
    const int r = tid >> 4, c = tid & 15;
    float s = b[c];
#pragma unroll
    for (int d = 0; d < D_DIM; ++d) s += Xsl[r * LSTR + d] * Ws[d * C_OUT + c];
    const int row = r0 + r;
    Y[row * C_OUT + c] = s;
    out[row * C_OUT + c] = s;
}

// ---------------------------------------------------------------- synthetic rows: lerp of Y
__global__ void syn_kernel(const float* __restrict__ Y, const int* __restrict__ nbrs,
                           const int* __restrict__ nn_idx, const float* __restrict__ gaps,
                           float* __restrict__ out) {
    const int idx = blockIdx.x * 256 + threadIdx.x;
    const int m = idx >> 4;
    const int c = idx & 15;
    const int src = m >> 2;       // repeat(arange(T), 4)
    const int sel = nn_idx[m];    // 0 or 1
    const int ch = nbrs[src * 2 + sel];
    const float g = gaps[m];
    const float ys = Y[src * C_OUT + c];
    const float yc = Y[ch * C_OUT + c];
    out[(T_PTS + m) * C_OUT + c] = ys + g * (yc - ys);
}

extern "C" void kernel_launch(void* const* d_in, const int* in_sizes, int n_in,
                              void* d_out, int out_size, void* d_ws, size_t ws_size,
                              hipStream_t stream) {
    const float* X = (const float*)d_in[0];
    const int* nn_idx = (const int*)d_in[1];
    const float* gaps = (const float*)d_in[2];
    const float* W = (const float*)d_in[3];
    const float* b = (const float*)d_in[4];
    float* out = (float*)d_out;

    char* ws = (char*)d_ws;
    _Float16* Xs = (_Float16*)ws;                        // 2 MB (swizzled fp16)
    float* sq = (float*)(ws + 2097152);                  // 32 KB
    float* ckey = (float*)(ws + 2129920);                // 1 MB
    ushort_t* cidx = (ushort_t*)(ws + 3178496);          // 512 KB
    ushort_t* nb8 = (ushort_t*)(ws + 3702784);           // 128 KB
    int* nbrs = (int*)(ws + 3833856);                    // 64 KB
    float* Y = (float*)(ws + 2129920 + 32768);           // overlaps ckey tail region? NO -> see below
    // Y must not alias anything live: ckey is dead after merge8; place Y over ckey.
    Y = (float*)(ws + 2129920);                          // 512 KB over dead ckey (y runs after merge8)

    prep_kernel<<<T_PTS / 16, 256, 0, stream>>>(X, Xs, sq);
    nn_kernel<<<dim3(T_PTS / 64, NSPLIT), 256, 0, stream>>>(Xs, sq, ckey, cidx);
    merge8_kernel<<<T_PTS / 256, 256, 0, stream>>>(ckey, cidx, nb8);
    rescore8_kernel<<<T_PTS / 32, 256, 0, stream>>>(X, sq, nb8, nbrs);
    y_kernel<<<T_PTS / 16, 256, 0, stream>>>(X, W, b, Y, out);
    syn_kernel<<<(4 * T_PTS * C_OUT) / 256, 256, 0, stream>>>(Y, nbrs, nn_idx, gaps, out);
}

// Round 11
// 111.159 us; speedup vs baseline: 1.4496x; 1.0653x over previous
//
#include <hip/hip_runtime.h>

#define T_PTS 8192
#define D_DIM 128
#define C_OUT 16
#define NSPLIT 8
#define JSPAN (T_PTS / NSPLIT) /* 1024 */
#define NJT (JSPAN / 64)       /* 16 */
#define LSTR 132               /* fp32 LDS stride for y kernel */

typedef _Float16 half8 __attribute__((ext_vector_type(8)));
typedef __attribute__((ext_vector_type(4))) float f32x4;
typedef unsigned short ushort_t;
typedef unsigned int uint_t;

// Swizzled fp16 layout: Xs[tile=row>>4][k=0..3][lane=quad*16+(row&15)][8 halfs]
// => af/bfrag loads are base + lane*16B: perfectly coalesced (R10-proven).

// ---------------------------------------------------------------- prep: fp32->fp16 swizzled + rowwise sumsq
__global__ void prep_kernel(const float* __restrict__ X, _Float16* __restrict__ Xs,
                            float* __restrict__ sq) {
    const int tid = threadIdx.x;
    const int row = blockIdx.x * 16 + (tid >> 4);
    const int ch = tid & 15;
    const float4* p = (const float4*)(X + row * D_DIM + ch * 8);
    const float4 a = p[0], b = p[1];
    half8 o;
    o[0] = (_Float16)a.x; o[1] = (_Float16)a.y; o[2] = (_Float16)a.z; o[3] = (_Float16)a.w;
    o[4] = (_Float16)b.x; o[5] = (_Float16)b.y; o[6] = (_Float16)b.z; o[7] = (_Float16)b.w;
    const int t = row >> 4, m = row & 15, k = ch >> 2, q = ch & 3;
    *(half8*)(Xs + t * 2048 + k * 512 + (q * 16 + m) * 8) = o;
    float s = a.x * a.x + a.y * a.y + a.z * a.z + a.w * a.w
            + b.x * b.x + b.y * b.y + b.z * b.z + b.w * b.w;
    s += __shfl_xor(s, 1); s += __shfl_xor(s, 2);
    s += __shfl_xor(s, 4); s += __shfl_xor(s, 8);
    if (ch == 0) sq[row] = s;
}

// sorted-4 chain insert via med3 (chain ascending), R8/R10-proven
#define INS4(c0_, c1_, c2_, c3_, v_)                         \
    do {                                                     \
        const float _v = (v_);                               \
        c3_ = __builtin_amdgcn_fmed3f(c2_, c3_, _v);         \
        c2_ = __builtin_amdgcn_fmed3f(c1_, c2_, _v);         \
        c1_ = __builtin_amdgcn_fmed3f(c0_, c1_, _v);         \
        c0_ = fminf(c0_, _v);                                \
    } while (0)

// ---------------------------------------------------------------- MFMA fp16 scores, barrier-light, prefetched
// fp16 keys are CANDIDATE-RECALL ONLY; fp32 rescore decides the final order.
// Packed key low 8 bits: [7:6]=quad, [5:0]=jt*4+r (<=255ulp perturbation, recall-safe).
// REGISTER BUDGET: bfrag 64 VGPR persistent — (256,2) mandatory; (256,4) spilled (round 7).
__launch_bounds__(256, 2)
__global__ void nn_kernel(const _Float16* __restrict__ Xs, const float* __restrict__ sq,
                          float* __restrict__ ckey, ushort_t* __restrict__ cidx) {
    __shared__ float mkLds[4][64][5];   // [wave][row][entry(4) + pad] packed keys, 5.1 KB

    const int tid = threadIdx.x;
    const int w = tid >> 6;
    const int lane = tid & 63;
    const int quad = lane >> 4;
    const int l15 = lane & 15;
    const int i0 = blockIdx.x * 64;
    const int sp = blockIdx.y;
    const int j0 = sp * JSPAN;

    // B-operand frags (i side): coalesced swizzled loads, held for the whole sweep
    half8 bfrag[4][4];
#pragma unroll
    for (int n = 0; n < 4; ++n)
#pragma unroll
        for (int k = 0; k < 4; ++k)
            bfrag[n][k] = *(const half8*)(Xs + ((i0 >> 4) + n) * 2048 + k * 512 + lane * 8);

    float c0[4], c1[4], c2[4], c3[4], sk[4];
#pragma unroll
    for (int n = 0; n < 4; ++n) { c0[n] = c1[n] = c2[n] = c3[n] = sk[n] = 1e30f; }

    const bool blk_excl = (sp == (i0 / JSPAN));
    const int excl_jt = (i0 & (JSPAN - 1)) >> 6;

    // prefetch jt=0
    half8 af[4];
    f32x4 sq4;
    {
        const int jtile = (j0 >> 4) + w;
#pragma unroll
        for (int k = 0; k < 4; ++k)
            af[k] = *(const half8*)(Xs + jtile * 2048 + k * 512 + lane * 8);
        sq4 = *(const f32x4*)(sq + j0 + w * 16 + quad * 4);
    }

#pragma unroll 2
    for (int jt = 0; jt < NJT; ++jt) {
        const int jbase = j0 + jt * 64;
        const int jg = jbase + w * 16 + quad * 4;  // + r
        // prefetch jt+1 (wraps harmlessly on last iter)
        half8 afn[4];
        f32x4 sq4n;
        {
            const int jb2 = j0 + ((jt + 1) & (NJT - 1)) * 64;
            const int jtile2 = (jb2 >> 4) + w;
#pragma unroll
            for (int k = 0; k < 4; ++k)
                afn[k] = *(const half8*)(Xs + jtile2 * 2048 + k * 512 + lane * 8);
            sq4n = *(const f32x4*)(sq + jb2 + w * 16 + quad * 4);
        }
        const bool excl = blk_excl && (jt == excl_jt);
        const uint_t ib = (uint_t)((quad << 6) | (jt * 4));

#pragma unroll
        for (int n = 0; n < 4; ++n) {
            f32x4 acc = {0.f, 0.f, 0.f, 0.f};
#pragma unroll
            for (int k = 0; k < 4; ++k)
                acc = __builtin_amdgcn_mfma_f32_16x16x32_f16(af[k], bfrag[n][k], acc, 0, 0, 0);
            float q0 = fmaf(-2.f, acc[0], sq4[0]);
            float q1 = fmaf(-2.f, acc[1], sq4[1]);
            float q2 = fmaf(-2.f, acc[2], sq4[2]);
            float q3 = fmaf(-2.f, acc[3], sq4[3]);
            if (excl) {  // wave-uniform; self-exclusion BEFORE packing/selection
                const int ic = i0 + n * 16 + l15;
                if (jg + 0 == ic) q0 = 1e30f;
                if (jg + 1 == ic) q1 = 1e30f;
                if (jg + 2 == ic) q2 = 1e30f;
                if (jg + 3 == ic) q3 = 1e30f;
            }
            const float p0 = __uint_as_float((__float_as_uint(q0) & 0xFFFFFF00u) | (ib + 0));
            const float p1 = __uint_as_float((__float_as_uint(q1) & 0xFFFFFF00u) | (ib + 1));
            const float p2 = __uint_as_float((__float_as_uint(q2) & 0xFFFFFF00u) | (ib + 2));
            const float p3 = __uint_as_float((__float_as_uint(q3) & 0xFFFFFF00u) | (ib + 3));
            const float min01 = fminf(p0, p1), max01 = fmaxf(p0, p1);
            const float min23 = fminf(p2, p3), max23 = fmaxf(p2, p3);
            const float kmin = fminf(min01, min23);
            const float ksec = fminf(fmaxf(min01, min23), fminf(max01, max23));
            INS4(c0[n], c1[n], c2[n], c3[n], kmin);
            sk[n] = fminf(sk[n], ksec);
        }
#pragma unroll
        for (int k = 0; k < 4; ++k) af[k] = afn[k];
        sq4 = sq4n;
    }

    // fold side value, then merge the 4 quad-chains in-register (shfl butterfly).
    // Each quad-chain provably contains its local top-3; exact merge keeps group top-3.
#pragma unroll
    for (int n = 0; n < 4; ++n) {
        INS4(c0[n], c1[n], c2[n], c3[n], sk[n]);
        float d0 = __shfl_xor(c0[n], 16), d1 = __shfl_xor(c1[n], 16);
        float d2 = __shfl_xor(c2[n], 16), d3 = __shfl_xor(c3[n], 16);
        INS4(c0[n], c1[n], c2[n], c3[n], d0);
        INS4(c0[n], c1[n], c2[n], c3[n], d1);
        INS4(c0[n], c1[n], c2[n], c3[n], d2);
        INS4(c0[n], c1[n], c2[n], c3[n], d3);
        d0 = __shfl_xor(c0[n], 32); d1 = __shfl_xor(c1[n], 32);
        d2 = __shfl_xor(c2[n], 32); d3 = __shfl_xor(c3[n], 32);
        INS4(c0[n], c1[n], c2[n], c3[n], d0);
        INS4(c0[n], c1[n], c2[n], c3[n], d1);
        INS4(c0[n], c1[n], c2[n], c3[n], d2);
        INS4(c0[n], c1[n], c2[n], c3[n], d3);
    }

    if (quad == 0) {
#pragma unroll
        for (int n = 0; n < 4; ++n) {
            const int row = n * 16 + l15;
            mkLds[w][row][0] = c0[n];
            mkLds[w][row][1] = c1[n];
            mkLds[w][row][2] = c2[n];
            mkLds[w][row][3] = c3[n];
        }
    }
    __syncthreads();
    if (tid < 64) {
        float a0 = 1e30f, a1 = 1e30f, a2 = 1e30f, a3 = 1e30f;
        int b0 = 0, b1 = 0, b2 = 0, b3 = 0;
#pragma unroll
        for (int wv = 0; wv < 4; ++wv)
#pragma unroll
            for (int e = 0; e < 4; ++e) {
                const float kk = mkLds[wv][tid][e];
                const uint_t p8 = __float_as_uint(kk) & 255u;
                const int j = j0 + (int)((p8 & 63u) >> 2) * 64 + wv * 16
                            + (int)((p8 >> 6) & 3u) * 4 + (int)(p8 & 3u);
                bool l0 = kk < a0, l1 = kk < a1, l2 = kk < a2, l3 = kk < a3;
                a3 = l2 ? a2 : (l3 ? kk : a3); b3 = l2 ? b2 : (l3 ? j : b3);
                a2 = l1 ? a1 : (l2 ? kk : a2); b2 = l1 ? b1 : (l2 ? j : b2);
                a1 = l0 ? a0 : (l1 ? kk : a1); b1 = l0 ? b0 : (l1 ? j : b1);
                a0 = l0 ? kk : a0;             b0 = l0 ? j : b0;
            }
        const int gi = i0 + tid;
        f32x4 kv = {a0, a1, a2, a3};
        *(f32x4*)(ckey + (sp * T_PTS + gi) * 4) = kv;
        ushort_t* c = cidx + (sp * T_PTS + gi) * 4;
        c[0] = (ushort_t)b0; c[1] = (ushort_t)b1; c[2] = (ushort_t)b2; c[3] = (ushort_t)b3;
    }
}

// ---------------------------------------------------------------- tail: global top-8 by fp16 key + exact fp32 rescore
// CRITICAL: rescore dot stays a per-thread sequential fma chain (`ssum += a.x*b2.x;` x4,
// loop over q) — the accumulation order that matched the reference in rounds 1/4/6/8/9/10.
__global__ void tail_kernel(const float* __restrict__ X, const float* __restrict__ sq,
                            const float* __restrict__ ckey, const ushort_t* __restrict__ cidx,
                            int* __restrict__ nbrs) {
    __shared__ ushort_t cLds[32][33];
    __shared__ ushort_t nb8s[32][8];
    __shared__ float keys[32][9];
    __shared__ int idxs[32][9];
    const int tid = threadIdx.x;
    const int ib0 = blockIdx.x * 32;

    if (tid < 32) {
        const int i = ib0 + tid;
        float c0 = 1e30f, c1 = 1e30f, c2 = 1e30f, c3 = 1e30f;
        float c4 = 1e30f, c5 = 1e30f, c6 = 1e30f, c7 = 1e30f;
#pragma unroll
        for (int sp2 = 0; sp2 < NSPLIT; ++sp2) {
            const f32x4 kk = *(const f32x4*)(ckey + (sp2 * T_PTS + i) * 4);
            ushort_t j4[4];
            *(uint2*)j4 = *(const uint2*)(cidx + (sp2 * T_PTS + i) * 4);
#pragma unroll
            for (int e4 = 0; e4 < 4; ++e4) {
                const uint_t e = (uint_t)(sp2 * 4 + e4);
                const float v = __uint_as_float((__float_as_uint(kk[e4]) & 0xFFFFFFC0u) | e);
                cLds[tid][e] = j4[e4];
                c7 = __builtin_amdgcn_fmed3f(c6, c7, v);
                c6 = __builtin_amdgcn_fmed3f(c5, c6, v);
                c5 = __builtin_amdgcn_fmed3f(c4, c5, v);
                c4 = __builtin_amdgcn_fmed3f(c3, c4, v);
                c3 = __builtin_amdgcn_fmed3f(c2, c3, v);
                c2 = __builtin_amdgcn_fmed3f(c1, c2, v);
                c1 = __builtin_amdgcn_fmed3f(c0, c1, v);
                c0 = fminf(c0, v);
            }
        }
        const float top[8] = {c0, c1, c2, c3, c4, c5, c6, c7};
#pragma unroll
        for (int r = 0; r < 8; ++r)
            nb8s[tid][r] = cLds[tid][__float_as_uint(top[r]) & 63u];
    }
    __syncthreads();
    {
        const int rr = tid >> 3, cc = tid & 7;
        const int i = ib0 + rr;
        const int j = (int)nb8s[rr][cc];
        const float4* xi = (const float4*)(X + i * D_DIM);
        const float4* xj = (const float4*)(X + j * D_DIM);
        float ssum = 0.f;
#pragma unroll
        for (int q = 0; q < 32; ++q) {
            const float4 a = xi[q], b2 = xj[q];
            ssum += a.x * b2.x; ssum += a.y * b2.y; ssum += a.z * b2.z; ssum += a.w * b2.w;
        }
        float key = sq[j] - 2.f * ssum;
        if (j == i) key = 1e30f;
        keys[rr][cc] = key;
        idxs[rr][cc] = j;
    }
    __syncthreads();
    if (tid < 32) {
        float m0 = 1e30f, m1 = 1e30f;
        int n0 = 0x7fffffff, n1 = 0x7fffffff;
#pragma unroll
        for (int e = 0; e < 8; ++e) {
            const float k = keys[tid][e];
            const int j = idxs[tid][e];
            bool lt0 = (k < m0) || (k == m0 && j < n0);
            bool lt1 = (k < m1) || (k == m1 && j < n1);
            if (lt0) { m1 = m0; n1 = n0; m0 = k; n0 = j; }
            else if (lt1) { m1 = k; n1 = j; }
        }
        const int i = ib0 + tid;
        nbrs[i * 2 + 0] = n0;
        nbrs[i * 2 + 1] = n1;
    }
}

// ---------------------------------------------------------------- Y = X@W + b; also logits rows [0,T)
__launch_bounds__(256)
__global__ void y_kernel(const float* __restrict__ X, const float* __restrict__ W,
                         const float* __restrict__ b, float* __restrict__ Y,
                         float* __restrict__ out) {
    __shared__ float Xsl[16 * LSTR];
    __shared__ float Ws[D_DIM * C_OUT];
    const int tid = threadIdx.x;
    const int r0 = blockIdx.x * 16;
    const float4* src = (const float4*)(X + r0 * D_DIM);
#pragma unroll
    for (int it = 0; it < 2; ++it) {
        int f = tid + it * 256;  // 0..511
        int row = f >> 5, kq = f & 31;
        *(float4*)(Xsl + row * LSTR + kq * 4) = src[row * 32 + kq];
    }
#pragma unroll
    for (int it = 0; it < 2; ++it) {
        int f = tid + it * 256;
        ((float4*)Ws)[f] = ((const float4*)W)[f];
    }
    __syncthreads();
    const int r = tid >> 4, c = tid & 15;
    float s = b[c];
#pragma unroll
    for (int d = 0; d < D_DIM; ++d) s += Xsl[r * LSTR + d] * Ws[d * C_OUT + c];
    const int row = r0 + r;
    Y[row * C_OUT + c] = s;
    out[row * C_OUT + c] = s;
}

// ---------------------------------------------------------------- synthetic rows: lerp of Y
__global__ void syn_kernel(const float* __restrict__ Y, const int* __restrict__ nbrs,
                           const int* __restrict__ nn_idx, const float* __restrict__ gaps,
                           float* __restrict__ out) {
    const int idx = blockIdx.x * 256 + threadIdx.x;
    const int m = idx >> 4;
    const int c = idx & 15;
    const int src = m >> 2;       // repeat(arange(T), 4)
    const int sel = nn_idx[m];    // 0 or 1
    const int ch = nbrs[src * 2 + sel];
    const float g = gaps[m];
    const float ys = Y[src * C_OUT + c];
    const float yc = Y[ch * C_OUT + c];
    out[(T_PTS + m) * C_OUT + c] = ys + g * (yc - ys);
}

extern "C" void kernel_launch(void* const* d_in, const int* in_sizes, int n_in,
                              void* d_out, int out_size, void* d_ws, size_t ws_size,
                              hipStream_t stream) {
    const float* X = (const float*)d_in[0];
    const int* nn_idx = (const int*)d_in[1];
    const float* gaps = (const float*)d_in[2];
    const float* W = (const float*)d_in[3];
    const float* b = (const float*)d_in[4];
    float* out = (float*)d_out;

    char* ws = (char*)d_ws;
    _Float16* Xs = (_Float16*)ws;                        // 2 MB (swizzled fp16)
    float* sq = (float*)(ws + 2097152);                  // 32 KB
    float* ckey = (float*)(ws + 2129920);                // 1 MB
    ushort_t* cidx = (ushort_t*)(ws + 3178496);          // 512 KB
    int* nbrs = (int*)(ws + 3702784);                    // 64 KB
    float* Y = (float*)(ws + 2129920);                   // 512 KB, over ckey (dead after tail_kernel)

    prep_kernel<<<T_PTS / 16, 256, 0, stream>>>(X, Xs, sq);
    nn_kernel<<<dim3(T_PTS / 64, NSPLIT), 256, 0, stream>>>(Xs, sq, ckey, cidx);
    tail_kernel<<<T_PTS / 32, 256, 0, stream>>>(X, sq, ckey, cidx, nbrs);
    y_kernel<<<T_PTS / 16, 256, 0, stream>>>(X, W, b, Y, out);
    syn_kernel<<<(4 * T_PTS * C_OUT) / 256, 256, 0, stream>>>(Y, nbrs, nn_idx, gaps, out);
}

// Round 12
// 105.013 us; speedup vs baseline: 1.5344x; 1.0585x over previous
//
#include <hip/hip_runtime.h>

#define T_PTS 8192
#define D_DIM 128
#define C_OUT 16
#define NSPLIT 4
#define JSPAN (T_PTS / NSPLIT) /* 2048 */
#define NJT (JSPAN / 64)       /* 32 */
#define LSTR 132               /* fp32 LDS stride for y part */
#define PREP_BLOCKS (T_PTS / 16)

typedef _Float16 half8 __attribute__((ext_vector_type(8)));
typedef __attribute__((ext_vector_type(4))) float f32x4;
typedef unsigned short ushort_t;
typedef unsigned int uint_t;

// Swizzled fp16 layout: Xs[tile=row>>4][k=0..3][lane=quad*16+(row&15)][8 halfs]
// => af/bfrag loads are base + lane*16B: perfectly coalesced (R10/R11-proven).

// sorted-4 chain insert via med3 (chain ascending), R8/R10/R11-proven
#define INS4(c0_, c1_, c2_, c3_, v_)                         \
    do {                                                     \
        const float _v = (v_);                               \
        c3_ = __builtin_amdgcn_fmed3f(c2_, c3_, _v);         \
        c2_ = __builtin_amdgcn_fmed3f(c1_, c2_, _v);         \
        c1_ = __builtin_amdgcn_fmed3f(c0_, c1_, _v);         \
        c0_ = fminf(c0_, _v);                                \
    } while (0)

// ---------------------------------------------------------------- prep: swizzle+sq  |  y = X@W+b (block ranges)
__global__ void prep_kernel(const float* __restrict__ X, _Float16* __restrict__ Xs,
                            float* __restrict__ sq, const float* __restrict__ W,
                            const float* __restrict__ b, float* __restrict__ Y,
                            float* __restrict__ out) {
    const int tid = threadIdx.x;
    if (blockIdx.x < PREP_BLOCKS) {
        const int row = blockIdx.x * 16 + (tid >> 4);
        const int ch = tid & 15;
        const float4* p = (const float4*)(X + row * D_DIM + ch * 8);
        const float4 a = p[0], bb = p[1];
        half8 o;
        o[0] = (_Float16)a.x;  o[1] = (_Float16)a.y;  o[2] = (_Float16)a.z;  o[3] = (_Float16)a.w;
        o[4] = (_Float16)bb.x; o[5] = (_Float16)bb.y; o[6] = (_Float16)bb.z; o[7] = (_Float16)bb.w;
        const int t = row >> 4, m = row & 15, k = ch >> 2, q = ch & 3;
        *(half8*)(Xs + t * 2048 + k * 512 + (q * 16 + m) * 8) = o;
        float s = a.x * a.x + a.y * a.y + a.z * a.z + a.w * a.w
                + bb.x * bb.x + bb.y * bb.y + bb.z * bb.z + bb.w * bb.w;
        s += __shfl_xor(s, 1); s += __shfl_xor(s, 2);
        s += __shfl_xor(s, 4); s += __shfl_xor(s, 8);
        if (ch == 0) sq[row] = s;
    } else {
        __shared__ float Xsl[16 * LSTR];
        __shared__ float Ws[D_DIM * C_OUT];
        const int r0 = (blockIdx.x - PREP_BLOCKS) * 16;
        const float4* src = (const float4*)(X + r0 * D_DIM);
#pragma unroll
        for (int it = 0; it < 2; ++it) {
            int f = tid + it * 256;  // 0..511
            int row = f >> 5, kq = f & 31;
            *(float4*)(Xsl + row * LSTR + kq * 4) = src[row * 32 + kq];
        }
#pragma unroll
        for (int it = 0; it < 2; ++it) {
            int f = tid + it * 256;
            ((float4*)Ws)[f] = ((const float4*)W)[f];
        }
        __syncthreads();
        const int r = tid >> 4, c = tid & 15;
        float s = b[c];
#pragma unroll
        for (int d = 0; d < D_DIM; ++d) s += Xsl[r * LSTR + d] * Ws[d * C_OUT + c];
        const int row = r0 + r;
        Y[row * C_OUT + c] = s;
        out[row * C_OUT + c] = s;
    }
}

// ---------------------------------------------------------------- MFMA fp16 scores, prefetched, shfl-merged
// fp16 keys are CANDIDATE-RECALL ONLY; fp32 rescore in tail decides the final order.
// Packed key low 9 bits: [8:7]=quad, [6:0]=jt*4+r (<=511ulp perturbation, recall-safe).
// REGISTER BUDGET: bfrag 64 VGPR persistent — (256,2) mandatory; (256,4) spilled (round 7).
__launch_bounds__(256, 2)
__global__ void nn_kernel(const _Float16* __restrict__ Xs, const float* __restrict__ sq,
                          float* __restrict__ ckey, ushort_t* __restrict__ cidx) {
    __shared__ float mkLds[4][64][5];   // [wave][row][entry(4)+pad], 5.1 KB

    const int tid = threadIdx.x;
    const int w = tid >> 6;
    const int lane = tid & 63;
    const int quad = lane >> 4;
    const int l15 = lane & 15;
    const int i0 = blockIdx.x * 64;
    const int sp = blockIdx.y;
    const int j0 = sp * JSPAN;

    half8 bfrag[4][4];
#pragma unroll
    for (int n = 0; n < 4; ++n)
#pragma unroll
        for (int k = 0; k < 4; ++k)
            bfrag[n][k] = *(const half8*)(Xs + ((i0 >> 4) + n) * 2048 + k * 512 + lane * 8);

    float c0[4], c1[4], c2[4], c3[4], sk[4];
#pragma unroll
    for (int n = 0; n < 4; ++n) { c0[n] = c1[n] = c2[n] = c3[n] = sk[n] = 1e30f; }

    const bool blk_excl = (sp == (i0 / JSPAN));
    const int excl_jt = (i0 & (JSPAN - 1)) >> 6;

    half8 af[4];
    f32x4 sq4;
    {
        const int jtile = (j0 >> 4) + w;
#pragma unroll
        for (int k = 0; k < 4; ++k)
            af[k] = *(const half8*)(Xs + jtile * 2048 + k * 512 + lane * 8);
        sq4 = *(const f32x4*)(sq + j0 + w * 16 + quad * 4);
    }

#pragma unroll 2
    for (int jt = 0; jt < NJT; ++jt) {
        const int jbase = j0 + jt * 64;
        const int jg = jbase + w * 16 + quad * 4;  // + r
        half8 afn[4];
        f32x4 sq4n;
        {
            const int jb2 = j0 + ((jt + 1) & (NJT - 1)) * 64;
            const int jtile2 = (jb2 >> 4) + w;
#pragma unroll
            for (int k = 0; k < 4; ++k)
                afn[k] = *(const half8*)(Xs + jtile2 * 2048 + k * 512 + lane * 8);
            sq4n = *(const f32x4*)(sq + jb2 + w * 16 + quad * 4);
        }
        const bool excl = blk_excl && (jt == excl_jt);
        const uint_t ib = (uint_t)((quad << 7) | (jt * 4));

#pragma unroll
        for (int n = 0; n < 4; ++n) {
            f32x4 acc = {0.f, 0.f, 0.f, 0.f};
#pragma unroll
            for (int k = 0; k < 4; ++k)
                acc = __builtin_amdgcn_mfma_f32_16x16x32_f16(af[k], bfrag[n][k], acc, 0, 0, 0);
            float q0 = fmaf(-2.f, acc[0], sq4[0]);
            float q1 = fmaf(-2.f, acc[1], sq4[1]);
            float q2 = fmaf(-2.f, acc[2], sq4[2]);
            float q3 = fmaf(-2.f, acc[3], sq4[3]);
            if (excl) {  // wave-uniform; self-exclusion BEFORE packing/selection
                const int ic = i0 + n * 16 + l15;
                if (jg + 0 == ic) q0 = 1e30f;
                if (jg + 1 == ic) q1 = 1e30f;
                if (jg + 2 == ic) q2 = 1e30f;
                if (jg + 3 == ic) q3 = 1e30f;
            }
            const float p0 = __uint_as_float((__float_as_uint(q0) & 0xFFFFFE00u) | (ib + 0));
            const float p1 = __uint_as_float((__float_as_uint(q1) & 0xFFFFFE00u) | (ib + 1));
            const float p2 = __uint_as_float((__float_as_uint(q2) & 0xFFFFFE00u) | (ib + 2));
            const float p3 = __uint_as_float((__float_as_uint(q3) & 0xFFFFFE00u) | (ib + 3));
            const float min01 = fminf(p0, p1), max01 = fmaxf(p0, p1);
            const float min23 = fminf(p2, p3), max23 = fmaxf(p2, p3);
            const float kmin = fminf(min01, min23);
            const float ksec = fminf(fmaxf(min01, min23), fminf(max01, max23));
            INS4(c0[n], c1[n], c2[n], c3[n], kmin);
            sk[n] = fminf(sk[n], ksec);
        }
#pragma unroll
        for (int k = 0; k < 4; ++k) af[k] = afn[k];
        sq4 = sq4n;
    }

    // fold side value, merge 4 quad-chains in-register (shfl butterfly; exact merge)
#pragma unroll
    for (int n = 0; n < 4; ++n) {
        INS4(c0[n], c1[n], c2[n], c3[n], sk[n]);
        float d0 = __shfl_xor(c0[n], 16), d1 = __shfl_xor(c1[n], 16);
        float d2 = __shfl_xor(c2[n], 16), d3 = __shfl_xor(c3[n], 16);
        INS4(c0[n], c1[n], c2[n], c3[n], d0);
        INS4(c0[n], c1[n], c2[n], c3[n], d1);
        INS4(c0[n], c1[n], c2[n], c3[n], d2);
        INS4(c0[n], c1[n], c2[n], c3[n], d3);
        d0 = __shfl_xor(c0[n], 32); d1 = __shfl_xor(c1[n], 32);
        d2 = __shfl_xor(c2[n], 32); d3 = __shfl_xor(c3[n], 32);
        INS4(c0[n], c1[n], c2[n], c3[n], d0);
        INS4(c0[n], c1[n], c2[n], c3[n], d1);
        INS4(c0[n], c1[n], c2[n], c3[n], d2);
        INS4(c0[n], c1[n], c2[n], c3[n], d3);
    }

    if (quad == 0) {
#pragma unroll
        for (int n = 0; n < 4; ++n) {
            const int row = n * 16 + l15;
            mkLds[w][row][0] = c0[n];
            mkLds[w][row][1] = c1[n];
            mkLds[w][row][2] = c2[n];
            mkLds[w][row][3] = c3[n];
        }
    }
    __syncthreads();
    if (tid < 64) {
        float a0 = 1e30f, a1 = 1e30f, a2 = 1e30f, a3 = 1e30f;
        int b0 = 0, b1 = 0, b2 = 0, b3 = 0;
#pragma unroll
        for (int wv = 0; wv < 4; ++wv)
#pragma unroll
            for (int e = 0; e < 4; ++e) {
                const float kk = mkLds[wv][tid][e];
                const uint_t p9 = __float_as_uint(kk) & 511u;
                const int j = j0 + (int)((p9 & 127u) >> 2) * 64 + wv * 16
                            + (int)(p9 >> 7) * 4 + (int)(p9 & 3u);
                bool l0 = kk < a0, l1 = kk < a1, l2 = kk < a2, l3 = kk < a3;
                a3 = l2 ? a2 : (l3 ? kk : a3); b3 = l2 ? b2 : (l3 ? j : b3);
                a2 = l1 ? a1 : (l2 ? kk : a2); b2 = l1 ? b1 : (l2 ? j : b2);
                a1 = l0 ? a0 : (l1 ? kk : a1); b1 = l0 ? b0 : (l1 ? j : b1);
                a0 = l0 ? kk : a0;             b0 = l0 ? j : b0;
            }
        const int gi = i0 + tid;
        f32x4 kv = {a0, a1, a2, a3};
        *(f32x4*)(ckey + (sp * T_PTS + gi) * 4) = kv;
        ushort_t* c = cidx + (sp * T_PTS + gi) * 4;
        c[0] = (ushort_t)b0; c[1] = (ushort_t)b1; c[2] = (ushort_t)b2; c[3] = (ushort_t)b3;
    }
}

// ---------------------------------------------------------------- tail: top-8 merge + exact fp32 rescore + syn
// CRITICAL: rescore dot stays a per-thread sequential fma chain (`ssum += a.x*b2.x;` x4,
// loop over q) — the accumulation order that matched the reference in rounds 1/4/6/8-11.
__global__ void tail_kernel(const float* __restrict__ X, const float* __restrict__ sq,
                            const float* __restrict__ ckey, const ushort_t* __restrict__ cidx,
                            const float* __restrict__ Y, const int* __restrict__ nn_idx,
                            const float* __restrict__ gaps, float* __restrict__ out) {
    __shared__ ushort_t cLds[32][17];
    __shared__ ushort_t nb8s[32][8];
    __shared__ float keys[32][9];
    __shared__ int idxs[32][9];
    __shared__ int nbr2[32][2];
    const int tid = threadIdx.x;
    const int ib0 = blockIdx.x * 32;

    if (tid < 32) {
        const int i = ib0 + tid;
        float c0 = 1e30f, c1 = 1e30f, c2 = 1e30f, c3 = 1e30f;
        float c4 = 1e30f, c5 = 1e30f, c6 = 1e30f, c7 = 1e30f;
#pragma unroll
        for (int sp2 = 0; sp2 < NSPLIT; ++sp2) {
            const f32x4 kk = *(const f32x4*)(ckey + (sp2 * T_PTS + i) * 4);
            ushort_t j4[4];
            *(uint2*)j4 = *(const uint2*)(cidx + (sp2 * T_PTS + i) * 4);
#pragma unroll
            for (int e4 = 0; e4 < 4; ++e4) {
                const uint_t e = (uint_t)(sp2 * 4 + e4);
                const float v = __uint_as_float((__float_as_uint(kk[e4]) & 0xFFFFFFF0u) | e);
                cLds[tid][e] = j4[e4];
                c7 = __builtin_amdgcn_fmed3f(c6, c7, v);
                c6 = __builtin_amdgcn_fmed3f(c5, c6, v);
                c5 = __builtin_amdgcn_fmed3f(c4, c5, v);
                c4 = __builtin_amdgcn_fmed3f(c3, c4, v);
                c3 = __builtin_amdgcn_fmed3f(c2, c3, v);
                c2 = __builtin_amdgcn_fmed3f(c1, c2, v);
                c1 = __builtin_amdgcn_fmed3f(c0, c1, v);
                c0 = fminf(c0, v);
            }
        }
        const float top[8] = {c0, c1, c2, c3, c4, c5, c6, c7};
#pragma unroll
        for (int r = 0; r < 8; ++r)
            nb8s[tid][r] = cLds[tid][__float_as_uint(top[r]) & 15u];
    }
    __syncthreads();
    {
        const int rr = tid >> 3, cc = tid & 7;
        const int i = ib0 + rr;
        const int j = (int)nb8s[rr][cc];
        const float4* xi = (const float4*)(X + i * D_DIM);
        const float4* xj = (const float4*)(X + j * D_DIM);
        float ssum = 0.f;
#pragma unroll
        for (int q = 0; q < 32; ++q) {
            const float4 a = xi[q], b2 = xj[q];
            ssum += a.x * b2.x; ssum += a.y * b2.y; ssum += a.z * b2.z; ssum += a.w * b2.w;
        }
        float key = sq[j] - 2.f * ssum;
        if (j == i) key = 1e30f;
        keys[rr][cc] = key;
        idxs[rr][cc] = j;
    }
    __syncthreads();
    if (tid < 32) {
        float m0 = 1e30f, m1 = 1e30f;
        int n0 = 0x7fffffff, n1 = 0x7fffffff;
#pragma unroll
        for (int e = 0; e < 8; ++e) {
            const float k = keys[tid][e];
            const int j = idxs[tid][e];
            bool lt0 = (k < m0) || (k == m0 && j < n0);
            bool lt1 = (k < m1) || (k == m1 && j < n1);
            if (lt0) { m1 = m0; n1 = n0; m0 = k; n0 = j; }
            else if (lt1) { m1 = k; n1 = j; }
        }
        nbr2[tid][0] = n0;
        nbr2[tid][1] = n1;
    }
    __syncthreads();
    // synthetic rows for this block's 32 sources (128 m-rows x 16 cols = 8/thread)
    {
        const int c = tid & 15;
        const int g16 = tid >> 4;  // 0..15
#pragma unroll
        for (int e = 0; e < 8; ++e) {
            const int m_local = g16 + 16 * e;       // 0..127
            const int src_local = m_local >> 2;
            const int m_global = ib0 * 4 + m_local; // = (ib0+src_local)*4 + rep
            const int sel = nn_idx[m_global];       // 0 or 1
            const int ch = nbr2[src_local][sel];
            const float g = gaps[m_global];
            const float ys = Y[(ib0 + src_local) * C_OUT + c];
            const float yc = Y[ch * C_OUT + c];
            out[(T_PTS + m_global) * C_OUT + c] = ys + g * (yc - ys);
        }
    }
}

extern "C" void kernel_launch(void* const* d_in, const int* in_sizes, int n_in,
                              void* d_out, int out_size, void* d_ws, size_t ws_size,
                              hipStream_t stream) {
    const float* X = (const float*)d_in[0];
    const int* nn_idx = (const int*)d_in[1];
    const float* gaps = (const float*)d_in[2];
    const float* W = (const float*)d_in[3];
    const float* b = (const float*)d_in[4];
    float* out = (float*)d_out;

    char* ws = (char*)d_ws;
    _Float16* Xs = (_Float16*)ws;                        // 2 MB (swizzled fp16)
    float* sq = (float*)(ws + 2097152);                  // 32 KB
    float* ckey = (float*)(ws + 2129920);                // 512 KB
    ushort_t* cidx = (ushort_t*)(ws + 2654208);          // 256 KB
    float* Y = (float*)(ws + 2916352);                   // 512 KB

    prep_kernel<<<2 * PREP_BLOCKS, 256, 0, stream>>>(X, Xs, sq, W, b, Y, out);
    nn_kernel<<<dim3(T_PTS / 64, NSPLIT), 256, 0, stream>>>(Xs, sq, ckey, cidx);
    tail_kernel<<<T_PTS / 32, 256, 0, stream>>>(X, sq, ckey, cidx, Y, nn_idx, gaps, out);
}